// Round 1
// baseline (115.566 us; speedup 1.0000x reference)
//
#include <hip/hip_runtime.h>
#include <hip/hip_bf16.h>
#include <stdint.h>

// Problem constants: B=2, S=2048, D=1024, H=16, hd=64, scale=1/8.
// Key insight: attention scores are head-independent => out = A @ V with
// A = softmax(-cdist(pos,pos)/8) causal, V = x@wv.T+bv (full D columns).

typedef __attribute__((ext_vector_type(8))) short bf16x8;
typedef __attribute__((ext_vector_type(4))) float f32x4;
typedef __attribute__((ext_vector_type(4))) unsigned short us4;

#define AS1(p) (const __attribute__((address_space(1))) unsigned int*)(p)
#define AS3(p) (__attribute__((address_space(3))) unsigned int*)(p)

__device__ __forceinline__ unsigned short f2bf(float f) {
  union { float f; unsigned u; } v; v.f = f;
  unsigned r = v.u + 0x7FFFu + ((v.u >> 16) & 1u);   // RNE
  return (unsigned short)(r >> 16);
}

// ---------------- cast fp32 -> bf16, vectorized ----------------
__global__ void k_cast(const float* __restrict__ in, unsigned short* __restrict__ out, int n4) {
  int i = blockIdx.x * 256 + threadIdx.x;
  if (i >= n4) return;
  float4 v = ((const float4*)in)[i];
  us4 o;
  o.x = f2bf(v.x); o.y = f2bf(v.y); o.z = f2bf(v.z); o.w = f2bf(v.w);
  *(us4*)(out + 4 * (size_t)i) = o;
}

// ---------------- pos = x @ w3d.T + b3d (fp32) ----------------
__global__ void k_pos(const float* __restrict__ x, const float* __restrict__ w3d,
                      const float* __restrict__ b3d, float* __restrict__ pos) {
  const int row = blockIdx.x;                 // 0..4095
  const float* xr = x + (size_t)row * 1024;
  float a0 = 0.f, a1 = 0.f, a2 = 0.f;
  for (int i = threadIdx.x; i < 1024; i += 256) {
    float xv = xr[i];
    a0 = fmaf(xv, w3d[i], a0);
    a1 = fmaf(xv, w3d[1024 + i], a1);
    a2 = fmaf(xv, w3d[2048 + i], a2);
  }
  #pragma unroll
  for (int off = 32; off; off >>= 1) {
    a0 += __shfl_down(a0, off, 64);
    a1 += __shfl_down(a1, off, 64);
    a2 += __shfl_down(a2, off, 64);
  }
  __shared__ float red[4][3];
  const int w = threadIdx.x >> 6;
  if ((threadIdx.x & 63) == 0) { red[w][0] = a0; red[w][1] = a1; red[w][2] = a2; }
  __syncthreads();
  if (threadIdx.x == 0) {
    pos[(size_t)row * 3 + 0] = red[0][0] + red[1][0] + red[2][0] + red[3][0] + b3d[0];
    pos[(size_t)row * 3 + 1] = red[0][1] + red[1][1] + red[2][1] + red[3][1] + b3d[1];
    pos[(size_t)row * 3 + 2] = red[0][2] + red[1][2] + red[2][2] + red[3][2] + b3d[2];
  }
}

// -------- A[b,q,:] = softmax_j<=q exp(-dist/8); zeros above diagonal --------
// Row max is always 0 (diagonal distance == 0), so no max reduction needed.
__global__ void k_attn(const float* __restrict__ pos, unsigned short* __restrict__ Ab) {
  const int row = blockIdx.x;                 // b*2048 + q
  const int q = row & 2047;
  const int b = row >> 11;
  const float* pb = pos + (size_t)(b << 11) * 3;
  const float qx = pb[q * 3], qy = pb[q * 3 + 1], qz = pb[q * 3 + 2];
  float p[8];
  float sum = 0.f;
  #pragma unroll
  for (int t = 0; t < 8; t++) {
    int j = threadIdx.x + (t << 8);
    float e = 0.f;
    if (j <= q) {
      float dx = qx - pb[j * 3], dy = qy - pb[j * 3 + 1], dz = qz - pb[j * 3 + 2];
      float sq = fmaf(dx, dx, fmaf(dy, dy, dz * dz));
      float d = sq > 0.f ? sqrtf(sq) : 0.f;
      e = __expf(-0.125f * d);
    }
    p[t] = e; sum += e;
  }
  #pragma unroll
  for (int off = 32; off; off >>= 1) sum += __shfl_down(sum, off, 64);
  __shared__ float red[4];
  if ((threadIdx.x & 63) == 0) red[threadIdx.x >> 6] = sum;
  __syncthreads();
  const float inv = 1.f / (red[0] + red[1] + red[2] + red[3]);
  unsigned short* orow = Ab + (size_t)row * 2048;
  #pragma unroll
  for (int t = 0; t < 8; t++) orow[threadIdx.x + (t << 8)] = f2bf(p[t] * inv);
}

// ---------------- shared NT-GEMM mainloop (m97 structure) ----------------
// C[m0..m0+128, n0..n0+128] += A[m,k] * Bt[n,k]; BK=32; 4 waves (2x2), each 64x64.
__device__ __forceinline__ void gemm_tile(
    const unsigned short* __restrict__ A, int lda,
    const unsigned short* __restrict__ Bt, int ldb,
    int m0, int n0, int kmax, f32x4 acc[4][4]) {
  __shared__ unsigned short lA[128 * 32];
  __shared__ unsigned short lB[128 * 32];
  const int tid = threadIdx.x;
  const int l = tid & 63;
  const int w = tid >> 6;
  const int wm = w >> 1, wn = w & 1;
  const int srow = l >> 2;              // staging row within 16-row chunk
  const int scol = (l & 3) << 3;        // staging col (elements)
  const int arow = wm * 64 + (l & 15);
  const int brow = wn * 64 + (l & 15);
  const int koff = (l >> 4) << 3;

  for (int k0 = 0; k0 < kmax; k0 += 32) {
    #pragma unroll
    for (int cc = 0; cc < 2; ++cc) {
      const int c = 2 * w + cc;               // chunk 0..7, wave-uniform
      const int r = c * 16 + srow;
      __builtin_amdgcn_global_load_lds(AS1(A + (size_t)(m0 + r) * lda + k0 + scol),
                                       AS3((char*)lA + c * 1024), 16, 0, 0);
      __builtin_amdgcn_global_load_lds(AS1(Bt + (size_t)(n0 + r) * ldb + k0 + scol),
                                       AS3((char*)lB + c * 1024), 16, 0, 0);
    }
    __syncthreads();
    bf16x8 af[4], bfr[4];
    #pragma unroll
    for (int i = 0; i < 4; i++) af[i] = *(const bf16x8*)&lA[(arow + i * 16) * 32 + koff];
    #pragma unroll
    for (int j = 0; j < 4; j++) bfr[j] = *(const bf16x8*)&lB[(brow + j * 16) * 32 + koff];
    #pragma unroll
    for (int i = 0; i < 4; i++)
      #pragma unroll
      for (int j = 0; j < 4; j++)
        acc[i][j] = __builtin_amdgcn_mfma_f32_16x16x32_bf16(af[i], bfr[j], acc[i][j], 0, 0, 0);
    __syncthreads();
  }
}

// GEMM1: V = xb @ wvb^T + bv, stored TRANSPOSED per batch: Vt[b][o][s]
__global__ __launch_bounds__(256, 2) void k_gemm_vproj(
    const unsigned short* __restrict__ xb, const unsigned short* __restrict__ wvb,
    const float* __restrict__ bv, unsigned short* __restrict__ Vt) {
  f32x4 acc[4][4] = {};
  const int m0 = blockIdx.x * 128, n0 = blockIdx.y * 128;
  gemm_tile(xb, 1024, wvb, 1024, m0, n0, 1024, acc);
  const int l = threadIdx.x & 63, w = threadIdx.x >> 6;
  const int wm = w >> 1, wn = w & 1;
  #pragma unroll
  for (int i = 0; i < 4; i++) {
    const int r0 = m0 + wm * 64 + i * 16 + ((l >> 4) << 2);
    const int b = r0 >> 11, s = r0 & 2047;
    #pragma unroll
    for (int j = 0; j < 4; j++) {
      const int cidx = n0 + wn * 64 + j * 16 + (l & 15);
      const float bias = bv[cidx];
      us4 o;
      o.x = f2bf(acc[i][j][0] + bias);
      o.y = f2bf(acc[i][j][1] + bias);
      o.z = f2bf(acc[i][j][2] + bias);
      o.w = f2bf(acc[i][j][3] + bias);
      *(us4*)(Vt + ((size_t)b << 21) + (size_t)cidx * 2048 + s) = o;
    }
  }
}

// GEMM2 (per batch): Ob[q][o] = sum_j A[q][j] * Vt[o][j]; causal K-cap.
__global__ __launch_bounds__(256, 2) void k_gemm_av(
    const unsigned short* __restrict__ Ab, const unsigned short* __restrict__ Vt,
    unsigned short* __restrict__ Ob) {
  f32x4 acc[4][4] = {};
  const int b = blockIdx.z;
  const int m0 = blockIdx.x * 128, n0 = blockIdx.y * 128;
  const unsigned short* A  = Ab + ((size_t)b << 22);
  const unsigned short* Bt = Vt + ((size_t)b << 21);
  gemm_tile(A, 2048, Bt, 2048, m0, n0, m0 + 128, acc);
  const int l = threadIdx.x & 63, w = threadIdx.x >> 6;
  const int wm = w >> 1, wn = w & 1;
  unsigned short* Obase = Ob + (((size_t)b << 11)) * 1024;
  #pragma unroll
  for (int i = 0; i < 4; i++) {
    const int r0 = m0 + wm * 64 + i * 16 + ((l >> 4) << 2);
    #pragma unroll
    for (int j = 0; j < 4; j++) {
      const int cidx = n0 + wn * 64 + j * 16 + (l & 15);
      #pragma unroll
      for (int t = 0; t < 4; t++)
        Obase[(size_t)(r0 + t) * 1024 + cidx] = f2bf(acc[i][j][t]);
    }
  }
}

// GEMM3: out = Ob @ wob^T + bo (fp32 out)
__global__ __launch_bounds__(256, 2) void k_gemm_out(
    const unsigned short* __restrict__ Ob, const unsigned short* __restrict__ wob,
    const float* __restrict__ bo, float* __restrict__ out) {
  f32x4 acc[4][4] = {};
  const int m0 = blockIdx.x * 128, n0 = blockIdx.y * 128;
  gemm_tile(Ob, 1024, wob, 1024, m0, n0, 1024, acc);
  const int l = threadIdx.x & 63, w = threadIdx.x >> 6;
  const int wm = w >> 1, wn = w & 1;
  #pragma unroll
  for (int i = 0; i < 4; i++) {
    const int r0 = m0 + wm * 64 + i * 16 + ((l >> 4) << 2);
    #pragma unroll
    for (int j = 0; j < 4; j++) {
      const int cidx = n0 + wn * 64 + j * 16 + (l & 15);
      const float bias = bo[cidx];
      #pragma unroll
      for (int t = 0; t < 4; t++)
        out[(size_t)(r0 + t) * 1024 + cidx] = acc[i][j][t] + bias;
    }
  }
}

extern "C" void kernel_launch(void* const* d_in, const int* in_sizes, int n_in,
                              void* d_out, int out_size, void* d_ws, size_t ws_size,
                              hipStream_t stream) {
  const float* x   = (const float*)d_in[0];
  const float* wv  = (const float*)d_in[5];
  const float* bv  = (const float*)d_in[6];
  const float* wo  = (const float*)d_in[7];
  const float* bo  = (const float*)d_in[8];
  const float* w3d = (const float*)d_in[9];
  const float* b3d = (const float*)d_in[10];
  float* out = (float*)d_out;

  char* ws = (char*)d_ws;
  unsigned short* xb  = (unsigned short*)(ws);               //  8 MB [4096][1024]
  unsigned short* wvb = (unsigned short*)(ws + (8u  << 20)); //  2 MB [1024][1024]
  unsigned short* wob = (unsigned short*)(ws + (10u << 20)); //  2 MB
  unsigned short* Vt  = (unsigned short*)(ws + (12u << 20)); //  8 MB [2][1024][2048]
  unsigned short* Ob  = (unsigned short*)(ws + (20u << 20)); //  8 MB [4096][1024]
  unsigned short* Ab  = (unsigned short*)(ws + (28u << 20)); // 16 MB [2][2048][2048]
  float*          pos = (float*)(ws + (44u << 20));          // 48 KB [4096][3]

  k_cast<<<4096, 256, 0, stream>>>(x,  xb,  1048576);
  k_cast<<<1024, 256, 0, stream>>>(wv, wvb, 262144);
  k_cast<<<1024, 256, 0, stream>>>(wo, wob, 262144);
  k_pos<<<4096, 256, 0, stream>>>(x, w3d, b3d, pos);
  k_attn<<<4096, 256, 0, stream>>>(pos, Ab);
  dim3 g1(32, 8, 1); k_gemm_vproj<<<g1, 256, 0, stream>>>(xb, wvb, bv, Vt);
  dim3 g2(16, 8, 2); k_gemm_av<<<g2, 256, 0, stream>>>(Ab, Vt, Ob);
  dim3 g3(32, 8, 1); k_gemm_out<<<g3, 256, 0, stream>>>(Ob, wob, bo, out);
}

// Round 2
// 79.613 us; speedup vs baseline: 1.4516x; 1.4516x over previous
//
#include <hip/hip_runtime.h>
#include <hip/hip_bf16.h>
#include <stdint.h>

// out = A @ (x @ Wc) + 1*cvec^T, where Wc = Wv^T Wo^T (so Bt-operand = Wo@Wv),
// A = causal softmax(-cdist(pos)/8) (head-independent, rows sum to 1),
// cvec = Wo@bv + bo. B=2, S=2048, D=1024.

typedef __attribute__((ext_vector_type(8))) short bf16x8;
typedef __attribute__((ext_vector_type(4))) float f32x4;
typedef __attribute__((ext_vector_type(4))) unsigned short us4;

#define AS1(p) (const __attribute__((address_space(1))) unsigned int*)(p)
#define AS3(p) (__attribute__((address_space(3))) unsigned int*)(p)

__device__ __forceinline__ unsigned short f2bf(float f) {
  union { float f; unsigned u; } v; v.f = f;
  unsigned r = v.u + 0x7FFFu + ((v.u >> 16) & 1u);   // RNE
  return (unsigned short)(r >> 16);
}

// ---------- k_prep: cast x->bf16 AND pos = x@w3d.T + b3d (reads x once) ----------
__global__ void k_prep(const float* __restrict__ x, const float* __restrict__ w3d,
                       const float* __restrict__ b3d, unsigned short* __restrict__ xb,
                       float* __restrict__ pos) {
  const int row = blockIdx.x, t = threadIdx.x;
  const float4 xv = ((const float4*)(x + (size_t)row * 1024))[t];
  us4 o; o.x = f2bf(xv.x); o.y = f2bf(xv.y); o.z = f2bf(xv.z); o.w = f2bf(xv.w);
  ((us4*)(xb + (size_t)row * 1024))[t] = o;
  const float4 w0 = ((const float4*)(w3d))[t];
  const float4 w1 = ((const float4*)(w3d + 1024))[t];
  const float4 w2 = ((const float4*)(w3d + 2048))[t];
  float a0 = xv.x*w0.x + xv.y*w0.y + xv.z*w0.z + xv.w*w0.w;
  float a1 = xv.x*w1.x + xv.y*w1.y + xv.z*w1.z + xv.w*w1.w;
  float a2 = xv.x*w2.x + xv.y*w2.y + xv.z*w2.z + xv.w*w2.w;
  #pragma unroll
  for (int off = 32; off; off >>= 1) {
    a0 += __shfl_down(a0, off, 64);
    a1 += __shfl_down(a1, off, 64);
    a2 += __shfl_down(a2, off, 64);
  }
  __shared__ float red[4][3];
  const int w = t >> 6;
  if ((t & 63) == 0) { red[w][0] = a0; red[w][1] = a1; red[w][2] = a2; }
  __syncthreads();
  if (t == 0) {
    pos[(size_t)row*3 + 0] = red[0][0]+red[1][0]+red[2][0]+red[3][0] + b3d[0];
    pos[(size_t)row*3 + 1] = red[0][1]+red[1][1]+red[2][1]+red[3][1] + b3d[1];
    pos[(size_t)row*3 + 2] = red[0][2]+red[1][2]+red[2][2]+red[3][2] + b3d[2];
  }
}

// ---------- k_castw: z=0 transpose-cast wv; z=1 cast wo + cvec = wo@bv + bo ----------
__global__ void k_castw(const float* __restrict__ wv, const float* __restrict__ wo,
                        const float* __restrict__ bv, const float* __restrict__ bo,
                        unsigned short* __restrict__ wvT, unsigned short* __restrict__ wob,
                        float* __restrict__ cvec) {
  __shared__ float ld[32][33];
  if (blockIdx.y == 0) {
    const int bx = blockIdx.x, tr = bx >> 5, tc = bx & 31;
    const int r = threadIdx.x >> 5, c = threadIdx.x & 31;
    #pragma unroll
    for (int rr = r; rr < 32; rr += 8)
      ld[rr][c] = wv[(size_t)(tr*32 + rr)*1024 + tc*32 + c];
    __syncthreads();
    #pragma unroll
    for (int rr = r; rr < 32; rr += 8)
      wvT[(size_t)(tc*32 + rr)*1024 + tr*32 + c] = f2bf(ld[c][rr]);
  } else {
    const int oo = blockIdx.x, t = threadIdx.x;
    const float4 w = ((const float4*)(wo + (size_t)oo*1024))[t];
    us4 ob; ob.x = f2bf(w.x); ob.y = f2bf(w.y); ob.z = f2bf(w.z); ob.w = f2bf(w.w);
    ((us4*)(wob + (size_t)oo*1024))[t] = ob;
    const float4 b = ((const float4*)bv)[t];
    float a = w.x*b.x + w.y*b.y + w.z*b.z + w.w*b.w;
    #pragma unroll
    for (int off = 32; off; off >>= 1) a += __shfl_down(a, off, 64);
    if ((t & 63) == 0) ld[0][t >> 6] = a;
    __syncthreads();
    if (t == 0) cvec[oo] = ld[0][0] + ld[0][1] + ld[0][2] + ld[0][3] + bo[oo];
  }
}

// ---------- k_attn: A[b,q,:] = causal softmax(-d/8); row max is 0 ----------
__global__ void k_attn(const float* __restrict__ pos, unsigned short* __restrict__ Ab) {
  const int row = blockIdx.x;
  const int q = row & 2047, bb = row >> 11;
  const float* pb = pos + ((size_t)bb << 11) * 3;
  const float qx = pb[q*3], qy = pb[q*3+1], qz = pb[q*3+2];
  const float4* pb4 = (const float4*)pb;
  float v[2][4];
  float sum = 0.f;
  #pragma unroll
  for (int cc = 0; cc < 2; cc++) {
    const int j0 = (cc << 10) + (threadIdx.x << 2);
    const float4 A4 = pb4[3*(j0 >> 2)], B4 = pb4[3*(j0 >> 2) + 1], C4 = pb4[3*(j0 >> 2) + 2];
    const float px[4] = {A4.x, A4.w, B4.z, C4.y};
    const float py[4] = {A4.y, B4.x, B4.w, C4.z};
    const float pz[4] = {A4.z, B4.y, C4.x, C4.w};
    #pragma unroll
    for (int u = 0; u < 4; u++) {
      float e = 0.f;
      if (j0 + u <= q) {
        float dx = qx - px[u], dy = qy - py[u], dz = qz - pz[u];
        float sq = fmaf(dx, dx, fmaf(dy, dy, dz*dz));
        float d = sq > 0.f ? sqrtf(sq) : 0.f;
        e = __expf(-0.125f * d);
      }
      v[cc][u] = e; sum += e;
    }
  }
  #pragma unroll
  for (int off = 32; off; off >>= 1) sum += __shfl_down(sum, off, 64);
  __shared__ float red[4];
  if ((threadIdx.x & 63) == 0) red[threadIdx.x >> 6] = sum;
  __syncthreads();
  const float inv = 1.f / (red[0] + red[1] + red[2] + red[3]);
  unsigned short* orow = Ab + (size_t)row * 2048;
  #pragma unroll
  for (int cc = 0; cc < 2; cc++) {
    us4 o;
    o.x = f2bf(v[cc][0]*inv); o.y = f2bf(v[cc][1]*inv);
    o.z = f2bf(v[cc][2]*inv); o.w = f2bf(v[cc][3]*inv);
    *(us4*)(orow + (cc << 10) + (threadIdx.x << 2)) = o;
  }
}

// ---------- templated NT GEMM mainloop: BK=64, dbuf LDS, 2-phase, XOR swizzle ----------
// LDS layout: row stride 128B (8 slots of 16B), slot' = slot ^ (row&7), applied on
// BOTH the pre-swizzled global source (stage) and the ds_read side (rule #21).
template<int BM, int BN, int WM, int WN>
__device__ __forceinline__ void gemm_loop(
    const unsigned short* __restrict__ A, int lda,
    const unsigned short* __restrict__ Bt, int ldb,
    int m0, int n0, int kmax,
    unsigned short* lds, f32x4* acc) {
  constexpr int WAVES = WM * WN;
  constexpr int FI = BM / (WM * 16), FJ = BN / (WN * 16);
  constexpr int CPW = ((BM + BN) / 8) / WAVES;
  unsigned short* lA = lds;                   // 2 * BM * 64
  unsigned short* lB = lds + 2 * BM * 64;     // 2 * BN * 64
  const int tid = threadIdx.x, l = tid & 63, w = tid >> 6;
  const int wm = w & (WM - 1), wn = w / WM;
  const int gcol = ((l & 7) ^ (l >> 3)) << 3;       // pre-swizzled k-chunk (elems)

  auto stage = [&](int buf, int k0) {
    #pragma unroll
    for (int e = 0; e < CPW; ++e) {
      const int c = w * CPW + e;                    // wave-uniform chunk (8 rows)
      const unsigned short* src;
      unsigned short* dst;
      if (c < BM / 8) {
        src = A + (size_t)(m0 + c*8 + (l >> 3)) * lda + k0 + gcol;
        dst = lA + buf * (BM * 64) + c * 512;
      } else {
        const int cb = c - BM / 8;
        src = Bt + (size_t)(n0 + cb*8 + (l >> 3)) * ldb + k0 + gcol;
        dst = lB + buf * (BN * 64) + cb * 512;
      }
      __builtin_amdgcn_global_load_lds(AS1(src), AS3(dst), 16, 0, 0);
    }
  };

  auto compute = [&](int buf) {
    #pragma unroll
    for (int h = 0; h < 2; ++h) {
      const int slot = ((h << 2) | (l >> 4)) ^ (l & 7);   // row&7 == l&7 for all frags
      bf16x8 af[FI], bfr[FJ];
      #pragma unroll
      for (int i = 0; i < FI; ++i) {
        const int ar = wm * (BM / WM) + i * 16 + (l & 15);
        af[i] = *(const bf16x8*)&lA[buf * (BM * 64) + ar * 64 + slot * 8];
      }
      #pragma unroll
      for (int j = 0; j < FJ; ++j) {
        const int br = wn * (BN / WN) + j * 16 + (l & 15);
        bfr[j] = *(const bf16x8*)&lB[buf * (BN * 64) + br * 64 + slot * 8];
      }
      #pragma unroll
      for (int i = 0; i < FI; ++i)
        #pragma unroll
        for (int j = 0; j < FJ; ++j)
          acc[i * FJ + j] = __builtin_amdgcn_mfma_f32_16x16x32_bf16(af[i], bfr[j], acc[i * FJ + j], 0, 0, 0);
    }
  };

  const int NT = kmax >> 6;
  stage(0, 0);
  __syncthreads();
  int cur = 0;
  for (int t = 0; t < NT; ++t) {
    if (t + 1 < NT) stage(cur ^ 1, (t + 1) << 6);
    compute(cur);
    __syncthreads();          // vmcnt(0)+lgkmcnt(0)+barrier: next buf ready
    cur ^= 1;
  }
}

// ---------- GEMM Wcs = wob @ wvT^T  (row-major [o][i] = (Wo Wv)[o][i]) ----------
__global__ __launch_bounds__(256) void k_gemm_wc(
    const unsigned short* __restrict__ wob, const unsigned short* __restrict__ wvT,
    unsigned short* __restrict__ Wcs) {
  __shared__ __align__(16) unsigned short lds[2 * 128 * 64];
  f32x4 acc[4] = {};
  const int m0 = blockIdx.x * 64, n0 = blockIdx.y * 64;
  gemm_loop<64, 64, 2, 2>(wob, 1024, wvT, 1024, m0, n0, 1024, lds, acc);
  const int l = threadIdx.x & 63, w = threadIdx.x >> 6;
  const int wm = w & 1, wn = w >> 1;
  #pragma unroll
  for (int i = 0; i < 2; i++) {
    const int r0 = m0 + wm*32 + i*16 + ((l >> 4) << 2);
    #pragma unroll
    for (int j = 0; j < 2; j++) {
      const int cidx = n0 + wn*32 + j*16 + (l & 15);
      #pragma unroll
      for (int t = 0; t < 4; t++)
        Wcs[(size_t)(r0 + t) * 1024 + cidx] = f2bf(acc[i*2 + j][t]);
    }
  }
}

// ---------- GEMM Yt[b][o][s] = (x @ Wc)[s][o]  (transposed write, bf16) ----------
__global__ __launch_bounds__(256) void k_gemm_y(
    const unsigned short* __restrict__ xb, const unsigned short* __restrict__ Wcs,
    unsigned short* __restrict__ Yt) {
  __shared__ __align__(16) unsigned short lds[2 * 256 * 64];
  f32x4 acc[16] = {};
  const int m0 = blockIdx.x * 128, n0 = blockIdx.y * 128;
  gemm_loop<128, 128, 2, 2>(xb, 1024, Wcs, 1024, m0, n0, 1024, lds, acc);
  const int l = threadIdx.x & 63, w = threadIdx.x >> 6;
  const int wm = w & 1, wn = w >> 1;
  #pragma unroll
  for (int i = 0; i < 4; i++) {
    const int r0 = m0 + wm*64 + i*16 + ((l >> 4) << 2);
    const int b = r0 >> 11, s = r0 & 2047;
    #pragma unroll
    for (int j = 0; j < 4; j++) {
      const int cidx = n0 + wn*64 + j*16 + (l & 15);
      us4 o;
      o.x = f2bf(acc[i*4 + j][0]); o.y = f2bf(acc[i*4 + j][1]);
      o.z = f2bf(acc[i*4 + j][2]); o.w = f2bf(acc[i*4 + j][3]);
      *(us4*)(Yt + ((size_t)b << 21) + (size_t)cidx * 2048 + s) = o;
    }
  }
}

// ---------- GEMM out[b,q,o] = sum_j A[q][j] Yt[o][j] + cvec[o]  (fp32 out) ----------
__global__ __launch_bounds__(256) void k_gemm_av(
    const unsigned short* __restrict__ Ab, const unsigned short* __restrict__ Yt,
    const float* __restrict__ cvec, float* __restrict__ out) {
  __shared__ __align__(16) unsigned short lds[2 * 256 * 64];
  f32x4 acc[16] = {};
  const int b = blockIdx.z, m0 = blockIdx.x * 128, n0 = blockIdx.y * 128;
  const unsigned short* A  = Ab + ((size_t)b << 22);
  const unsigned short* Bt = Yt + ((size_t)b << 21);
  gemm_loop<128, 128, 2, 2>(A, 2048, Bt, 2048, m0, n0, m0 + 128, lds, acc);  // causal K-cap
  float* Ob = out + ((size_t)b << 11) * 1024;
  const int l = threadIdx.x & 63, w = threadIdx.x >> 6;
  const int wm = w & 1, wn = w >> 1;
  #pragma unroll
  for (int i = 0; i < 4; i++) {
    const int r0 = m0 + wm*64 + i*16 + ((l >> 4) << 2);
    #pragma unroll
    for (int j = 0; j < 4; j++) {
      const int cidx = n0 + wn*64 + j*16 + (l & 15);
      const float cv = cvec[cidx];
      #pragma unroll
      for (int t = 0; t < 4; t++)
        Ob[(size_t)(r0 + t) * 1024 + cidx] = acc[i*4 + j][t] + cv;
    }
  }
}

extern "C" void kernel_launch(void* const* d_in, const int* in_sizes, int n_in,
                              void* d_out, int out_size, void* d_ws, size_t ws_size,
                              hipStream_t stream) {
  const float* x   = (const float*)d_in[0];
  const float* wv  = (const float*)d_in[5];
  const float* bv  = (const float*)d_in[6];
  const float* wo  = (const float*)d_in[7];
  const float* bo  = (const float*)d_in[8];
  const float* w3d = (const float*)d_in[9];
  const float* b3d = (const float*)d_in[10];
  float* out = (float*)d_out;

  char* ws = (char*)d_ws;
  unsigned short* xb  = (unsigned short*)(ws);                //  8 MB [4096][1024]
  unsigned short* wvT = (unsigned short*)(ws + ( 8u << 20));  //  2 MB [1024][1024] = wv^T
  unsigned short* wob = (unsigned short*)(ws + (10u << 20));  //  2 MB
  unsigned short* Wcs = (unsigned short*)(ws + (12u << 20));  //  2 MB (Wo@Wv)[o][i]
  unsigned short* Yt  = (unsigned short*)(ws + (14u << 20));  //  8 MB [2][1024][2048]
  unsigned short* Ab  = (unsigned short*)(ws + (22u << 20));  // 16 MB [2][2048][2048]
  float*          pos = (float*)(ws + (38u << 20));           // 48 KB
  float*          cvec= (float*)(ws + (39u << 20));           //  4 KB

  k_castw<<<dim3(1024, 2), 256, 0, stream>>>(wv, wo, bv, bo, wvT, wob, cvec);
  k_prep<<<4096, 256, 0, stream>>>(x, w3d, b3d, xb, pos);
  k_gemm_wc<<<dim3(16, 16), 256, 0, stream>>>(wob, wvT, Wcs);
  k_attn<<<4096, 256, 0, stream>>>(pos, Ab);
  k_gemm_y<<<dim3(32, 8), 256, 0, stream>>>(xb, Wcs, Yt);
  k_gemm_av<<<dim3(16, 8, 2), 256, 0, stream>>>(Ab, Yt, cvec, out);
}

// Round 3
// 76.314 us; speedup vs baseline: 1.5144x; 1.0432x over previous
//
#include <hip/hip_runtime.h>
#include <hip/hip_bf16.h>
#include <stdint.h>

// Pipeline: out = (A @ x) @ Wc + cvec, where Wc^T = Wcs = Wo@Wv (bf16),
// A = causal softmax(-cdist(pos)/8) (head-independent, rows sum to 1),
// cvec = Wo@bv + bo. B=2, S=2048, D=1024.

typedef __attribute__((ext_vector_type(8))) short bf16x8;
typedef __attribute__((ext_vector_type(4))) float f32x4;
typedef __attribute__((ext_vector_type(4))) unsigned short us4;

#define AS1(p) (const __attribute__((address_space(1))) unsigned int*)(p)
#define AS3(p) (__attribute__((address_space(3))) unsigned int*)(p)

__device__ __forceinline__ unsigned short f2bf(float f) {
  union { float f; unsigned u; } v; v.f = f;
  unsigned r = v.u + 0x7FFFu + ((v.u >> 16) & 1u);   // RNE
  return (unsigned short)(r >> 16);
}

// ---------- k_prep: 4 block-uniform branches ----------
// [0,1024):    x -> xT[b][d][s] bf16 (64x64 tiled transpose-cast)
// [1024,2048): wv -> wvT bf16 (32x32 tiled transpose-cast)
// [2048,3072): wo -> wob bf16 cast; cvec = wo@bv + bo
// [3072,7168): pos = x @ w3d.T + b3d
__global__ void k_prep(const float* __restrict__ x, const float* __restrict__ wv,
                       const float* __restrict__ wo, const float* __restrict__ bv,
                       const float* __restrict__ bo, const float* __restrict__ w3d,
                       const float* __restrict__ b3d,
                       unsigned short* __restrict__ xT, unsigned short* __restrict__ wvT,
                       unsigned short* __restrict__ wob, float* __restrict__ cvec,
                       float* __restrict__ pos) {
  __shared__ __align__(16) float lsm[64 * 68];
  const int bx = blockIdx.x, t = threadIdx.x;
  if (bx < 1024) {
    const int b = bx >> 9, rest = bx & 511, st = rest >> 4, dt = rest & 15;
    const int s0 = st * 64, d0 = dt * 64;
    const int r = t >> 2, c4 = t & 3;
    const float* src = x + (size_t)(b * 2048 + s0 + r) * 1024 + d0;
    float (*ld)[68] = (float(*)[68])lsm;
    #pragma unroll
    for (int p = 0; p < 4; p++)
      *(float4*)&ld[r][(c4 + 4 * p) * 4] = ((const float4*)src)[c4 + 4 * p];
    __syncthreads();
    #pragma unroll
    for (int p = 0; p < 4; p++) {
      const int dl = (t >> 4) + (p << 4);
      us4 o;
      #pragma unroll
      for (int k = 0; k < 4; k++)
        ((unsigned short*)&o)[k] = f2bf(ld[(t & 15) * 4 + k][dl]);
      *(us4*)(xT + ((size_t)b << 21) + (size_t)(d0 + dl) * 2048 + s0 + (t & 15) * 4) = o;
    }
  } else if (bx < 2048) {
    const int bb = bx - 1024, tr = bb >> 5, tc = bb & 31;
    const int r = t >> 5, c = t & 31;
    float (*ld)[33] = (float(*)[33])lsm;
    #pragma unroll
    for (int rr = r; rr < 32; rr += 8)
      ld[rr][c] = wv[(size_t)(tr * 32 + rr) * 1024 + tc * 32 + c];
    __syncthreads();
    #pragma unroll
    for (int rr = r; rr < 32; rr += 8)
      wvT[(size_t)(tc * 32 + rr) * 1024 + tr * 32 + c] = f2bf(ld[c][rr]);
  } else if (bx < 3072) {
    const int oo = bx - 2048;
    const float4 w = ((const float4*)(wo + (size_t)oo * 1024))[t];
    us4 ob; ob.x = f2bf(w.x); ob.y = f2bf(w.y); ob.z = f2bf(w.z); ob.w = f2bf(w.w);
    ((us4*)(wob + (size_t)oo * 1024))[t] = ob;
    const float4 b = ((const float4*)bv)[t];
    float a = w.x * b.x + w.y * b.y + w.z * b.z + w.w * b.w;
    #pragma unroll
    for (int off = 32; off; off >>= 1) a += __shfl_down(a, off, 64);
    if ((t & 63) == 0) lsm[t >> 6] = a;
    __syncthreads();
    if (t == 0) cvec[oo] = lsm[0] + lsm[1] + lsm[2] + lsm[3] + bo[oo];
  } else {
    const int row = bx - 3072;
    const float4 xv = ((const float4*)(x + (size_t)row * 1024))[t];
    const float4 w0 = ((const float4*)(w3d))[t];
    const float4 w1 = ((const float4*)(w3d + 1024))[t];
    const float4 w2 = ((const float4*)(w3d + 2048))[t];
    float a0 = xv.x*w0.x + xv.y*w0.y + xv.z*w0.z + xv.w*w0.w;
    float a1 = xv.x*w1.x + xv.y*w1.y + xv.z*w1.z + xv.w*w1.w;
    float a2 = xv.x*w2.x + xv.y*w2.y + xv.z*w2.z + xv.w*w2.w;
    #pragma unroll
    for (int off = 32; off; off >>= 1) {
      a0 += __shfl_down(a0, off, 64);
      a1 += __shfl_down(a1, off, 64);
      a2 += __shfl_down(a2, off, 64);
    }
    if ((t & 63) == 0) { lsm[(t >> 6) * 3] = a0; lsm[(t >> 6) * 3 + 1] = a1; lsm[(t >> 6) * 3 + 2] = a2; }
    __syncthreads();
    if (t == 0) {
      pos[(size_t)row*3 + 0] = lsm[0] + lsm[3] + lsm[6] + lsm[9]  + b3d[0];
      pos[(size_t)row*3 + 1] = lsm[1] + lsm[4] + lsm[7] + lsm[10] + b3d[1];
      pos[(size_t)row*3 + 2] = lsm[2] + lsm[5] + lsm[8] + lsm[11] + b3d[2];
    }
  }
}

// ---------- k_attn: A[b,q,:] = causal softmax(-d/8); row max is 0 ----------
__global__ void k_attn(const float* __restrict__ pos, unsigned short* __restrict__ Ab) {
  const int row = blockIdx.x;
  const int q = row & 2047, bb = row >> 11;
  const float* pb = pos + ((size_t)bb << 11) * 3;
  const float qx = pb[q*3], qy = pb[q*3+1], qz = pb[q*3+2];
  const float4* pb4 = (const float4*)pb;
  float v[2][4];
  float sum = 0.f;
  #pragma unroll
  for (int cc = 0; cc < 2; cc++) {
    const int j0 = (cc << 10) + (threadIdx.x << 2);
    const float4 A4 = pb4[3*(j0 >> 2)], B4 = pb4[3*(j0 >> 2) + 1], C4 = pb4[3*(j0 >> 2) + 2];
    const float px[4] = {A4.x, A4.w, B4.z, C4.y};
    const float py[4] = {A4.y, B4.x, B4.w, C4.z};
    const float pz[4] = {A4.z, B4.y, C4.x, C4.w};
    #pragma unroll
    for (int u = 0; u < 4; u++) {
      float e = 0.f;
      if (j0 + u <= q) {
        float dx = qx - px[u], dy = qy - py[u], dz = qz - pz[u];
        float sq = fmaf(dx, dx, fmaf(dy, dy, dz*dz));
        float d = sq > 0.f ? sqrtf(sq) : 0.f;
        e = __expf(-0.125f * d);
      }
      v[cc][u] = e; sum += e;
    }
  }
  #pragma unroll
  for (int off = 32; off; off >>= 1) sum += __shfl_down(sum, off, 64);
  __shared__ float red[4];
  if ((threadIdx.x & 63) == 0) red[threadIdx.x >> 6] = sum;
  __syncthreads();
  const float inv = 1.f / (red[0] + red[1] + red[2] + red[3]);
  unsigned short* orow = Ab + (size_t)row * 2048;
  #pragma unroll
  for (int cc = 0; cc < 2; cc++) {
    us4 o;
    o.x = f2bf(v[cc][0]*inv); o.y = f2bf(v[cc][1]*inv);
    o.z = f2bf(v[cc][2]*inv); o.w = f2bf(v[cc][3]*inv);
    *(us4*)(orow + (cc << 10) + (threadIdx.x << 2)) = o;
  }
}

// ---------- templated NT GEMM mainloop: BK=64, dbuf LDS, 2-phase, XOR swizzle ----------
template<int BM, int BN, int WM, int WN>
__device__ __forceinline__ void gemm_loop(
    const unsigned short* __restrict__ A, int lda,
    const unsigned short* __restrict__ Bt, int ldb,
    int m0, int n0, int kmax,
    unsigned short* lds, f32x4* acc) {
  constexpr int WAVES = WM * WN;
  constexpr int FI = BM / (WM * 16), FJ = BN / (WN * 16);
  constexpr int CPW = ((BM + BN) / 8) / WAVES;
  unsigned short* lA = lds;                   // 2 * BM * 64
  unsigned short* lB = lds + 2 * BM * 64;     // 2 * BN * 64
  const int tid = threadIdx.x, l = tid & 63, w = tid >> 6;
  const int wm = w & (WM - 1), wn = w / WM;
  const int gcol = ((l & 7) ^ (l >> 3)) << 3;       // pre-swizzled k-chunk (elems)

  auto stage = [&](int buf, int k0) {
    #pragma unroll
    for (int e = 0; e < CPW; ++e) {
      const int c = w * CPW + e;                    // wave-uniform chunk (8 rows)
      const unsigned short* src;
      unsigned short* dst;
      if (c < BM / 8) {
        src = A + (size_t)(m0 + c*8 + (l >> 3)) * lda + k0 + gcol;
        dst = lA + buf * (BM * 64) + c * 512;
      } else {
        const int cb = c - BM / 8;
        src = Bt + (size_t)(n0 + cb*8 + (l >> 3)) * ldb + k0 + gcol;
        dst = lB + buf * (BN * 64) + cb * 512;
      }
      __builtin_amdgcn_global_load_lds(AS1(src), AS3(dst), 16, 0, 0);
    }
  };

  auto compute = [&](int buf) {
    #pragma unroll
    for (int h = 0; h < 2; ++h) {
      const int slot = ((h << 2) | (l >> 4)) ^ (l & 7);
      bf16x8 af[FI], bfr[FJ];
      #pragma unroll
      for (int i = 0; i < FI; ++i) {
        const int ar = wm * (BM / WM) + i * 16 + (l & 15);
        af[i] = *(const bf16x8*)&lA[buf * (BM * 64) + ar * 64 + slot * 8];
      }
      #pragma unroll
      for (int j = 0; j < FJ; ++j) {
        const int br = wn * (BN / WN) + j * 16 + (l & 15);
        bfr[j] = *(const bf16x8*)&lB[buf * (BN * 64) + br * 64 + slot * 8];
      }
      #pragma unroll
      for (int i = 0; i < FI; ++i)
        #pragma unroll
        for (int j = 0; j < FJ; ++j)
          acc[i * FJ + j] = __builtin_amdgcn_mfma_f32_16x16x32_bf16(af[i], bfr[j], acc[i * FJ + j], 0, 0, 0);
    }
  };

  const int NT = kmax >> 6;
  stage(0, 0);
  __syncthreads();
  int cur = 0;
  for (int t = 0; t < NT; ++t) {
    if (t + 1 < NT) stage(cur ^ 1, (t + 1) << 6);
    compute(cur);
    __syncthreads();
    cur ^= 1;
  }
}

// ---------- Wcs = wob @ wvT^T = Wo@Wv, row-major [o][i], BM=BN=128 ----------
__global__ __launch_bounds__(256) void k_gemm_wc(
    const unsigned short* __restrict__ wob, const unsigned short* __restrict__ wvT,
    unsigned short* __restrict__ Wcs) {
  __shared__ __align__(16) unsigned short lds[2 * 256 * 64];
  f32x4 acc[16] = {};
  const int m0 = blockIdx.x * 128, n0 = blockIdx.y * 128;
  gemm_loop<128, 128, 2, 2>(wob, 1024, wvT, 1024, m0, n0, 1024, lds, acc);
  const int l = threadIdx.x & 63, w = threadIdx.x >> 6;
  const int wm = w & 1, wn = w >> 1;
  #pragma unroll
  for (int i = 0; i < 4; i++) {
    const int r0 = m0 + wm*64 + i*16 + ((l >> 4) << 2);
    #pragma unroll
    for (int j = 0; j < 4; j++) {
      const int cidx = n0 + wn*64 + j*16 + (l & 15);
      #pragma unroll
      for (int t = 0; t < 4; t++)
        Wcs[(size_t)(r0 + t) * 1024 + cidx] = f2bf(acc[i*4 + j][t]);
    }
  }
}

// ---------- Axb[b*2048+q][d] = sum_j A[q][j] xT[d][j], causal K-cap ----------
// BM=128, BN=64; grid (16 mi-reversed, 16 n, 2 b) = 512 blocks, 2/CU.
__global__ __launch_bounds__(256, 2) void k_gemm_ax(
    const unsigned short* __restrict__ Ab, const unsigned short* __restrict__ xT,
    unsigned short* __restrict__ Axb) {
  __shared__ __align__(16) unsigned short lds[2*128*64 + 2*64*64];
  f32x4 acc[8] = {};
  const int b = blockIdx.z;
  const int mi = 15 - blockIdx.x;               // long tiles dispatch first
  const int m0 = mi * 128, n0 = blockIdx.y * 64;
  const unsigned short* A  = Ab + ((size_t)b << 22);
  const unsigned short* Bt = xT + ((size_t)b << 21);
  gemm_loop<128, 64, 2, 2>(A, 2048, Bt, 2048, m0, n0, m0 + 128, lds, acc);
  const int l = threadIdx.x & 63, w = threadIdx.x >> 6;
  const int wm = w & 1, wn = w >> 1;
  unsigned short* Obase = Axb + ((size_t)b << 11) * 1024;
  #pragma unroll
  for (int i = 0; i < 4; i++) {
    const int r0 = m0 + wm*64 + i*16 + ((l >> 4) << 2);
    #pragma unroll
    for (int j = 0; j < 2; j++) {
      const int cidx = n0 + wn*32 + j*16 + (l & 15);
      #pragma unroll
      for (int t = 0; t < 4; t++)
        Obase[(size_t)(r0 + t) * 1024 + cidx] = f2bf(acc[i*2 + j][t]);
    }
  }
}

// ---------- out[r][o] = sum_d Axb[r][d] Wcs[o][d] + cvec[o] (fp32) ----------
// BM=128, BN=64; grid (32 m, 16 n) = 512 blocks, 2/CU; m in x for XCD-L2 locality.
__global__ __launch_bounds__(256, 2) void k_gemm_out(
    const unsigned short* __restrict__ Axb, const unsigned short* __restrict__ Wcs,
    const float* __restrict__ cvec, float* __restrict__ out) {
  __shared__ __align__(16) unsigned short lds[2*128*64 + 2*64*64];
  f32x4 acc[8] = {};
  const int m0 = blockIdx.x * 128, n0 = blockIdx.y * 64;
  gemm_loop<128, 64, 2, 2>(Axb, 1024, Wcs, 1024, m0, n0, 1024, lds, acc);
  const int l = threadIdx.x & 63, w = threadIdx.x >> 6;
  const int wm = w & 1, wn = w >> 1;
  #pragma unroll
  for (int i = 0; i < 4; i++) {
    const int r0 = m0 + wm*64 + i*16 + ((l >> 4) << 2);
    #pragma unroll
    for (int j = 0; j < 2; j++) {
      const int cidx = n0 + wn*32 + j*16 + (l & 15);
      const float cv = cvec[cidx];
      #pragma unroll
      for (int t = 0; t < 4; t++)
        out[(size_t)(r0 + t) * 1024 + cidx] = acc[i*2 + j][t] + cv;
    }
  }
}

extern "C" void kernel_launch(void* const* d_in, const int* in_sizes, int n_in,
                              void* d_out, int out_size, void* d_ws, size_t ws_size,
                              hipStream_t stream) {
  const float* x   = (const float*)d_in[0];
  const float* wv  = (const float*)d_in[5];
  const float* bv  = (const float*)d_in[6];
  const float* wo  = (const float*)d_in[7];
  const float* bo  = (const float*)d_in[8];
  const float* w3d = (const float*)d_in[9];
  const float* b3d = (const float*)d_in[10];
  float* out = (float*)d_out;

  char* ws = (char*)d_ws;
  unsigned short* xT  = (unsigned short*)(ws);                //  8 MB [2][1024][2048]
  unsigned short* wvT = (unsigned short*)(ws + ( 8u << 20));  //  2 MB wv^T
  unsigned short* wob = (unsigned short*)(ws + (10u << 20));  //  2 MB
  unsigned short* Wcs = (unsigned short*)(ws + (12u << 20));  //  2 MB (Wo@Wv)[o][i]
  unsigned short* Axb = (unsigned short*)(ws + (14u << 20));  //  8 MB [4096][1024]
  unsigned short* Ab  = (unsigned short*)(ws + (22u << 20));  // 16 MB [2][2048][2048]
  float*          pos = (float*)(ws + (38u << 20));           // 48 KB
  float*          cvec= (float*)(ws + (39u << 20));           //  4 KB

  k_prep<<<7168, 256, 0, stream>>>(x, wv, wo, bv, bo, w3d, b3d, xT, wvT, wob, cvec, pos);
  k_attn<<<4096, 256, 0, stream>>>(pos, Ab);
  k_gemm_wc<<<dim3(8, 8), 256, 0, stream>>>(wob, wvT, Wcs);
  k_gemm_ax<<<dim3(16, 16, 2), 256, 0, stream>>>(Ab, xT, Axb);
  k_gemm_out<<<dim3(32, 16), 256, 0, stream>>>(Axb, Wcs, cvec, out);
}